// Round 3
// baseline (9410.680 us; speedup 1.0000x reference)
//
#include <hip/hip_runtime.h>
#include <cstdint>
#include <cstddef>

using u16 = unsigned short;
using u32 = unsigned int;

typedef __attribute__((ext_vector_type(8)))  __bf16 bf16x8;
typedef __attribute__((ext_vector_type(16))) float  f32x16;

constexpr int kB   = 512;
constexpr int kT   = 180;
constexpr int kH   = 768;
constexpr int NBLK = 192;   // 3 layers * (4 m-tiles * 16 n-tiles)

constexpr int L0N  = 16 * 192 * 832;    // layer0 packed weight elems (26 chunks of 32)
constexpr int L12N = 16 * 192 * 1536;   // layer1/2 (48 chunks)

// h-ring: chunked layout [2 slots][24 kchunks][512 rows][32 k] bf16
constexpr int RING_SLOT_E = 24 * 512 * 32;               // 393,216 elems per slot
constexpr size_t RING_SZ  = (size_t)2 * RING_SLOT_E * 2; // 1,572,864 B

// workspace layout (bytes)
constexpr size_t OFF_R0  = 256;
constexpr size_t OFF_R1  = OFF_R0 + RING_SZ;
constexpr size_t OFF_R2  = OFF_R1 + RING_SZ;
constexpr size_t OFF_PB  = OFF_R2 + RING_SZ;             // zeroed region end
constexpr size_t OFF_XT  = OFF_PB + (size_t)3 * 3072 * 4;
constexpr size_t OFF_W0  = OFF_XT + (size_t)kT * kB * 64 * 2;
constexpr size_t OFF_W1  = OFF_W0 + (size_t)L0N * 2;
constexpr size_t OFF_W2  = OFF_W1 + (size_t)L12N * 2;
constexpr size_t WS_NEED = OFF_W2 + (size_t)L12N * 2;    // ~40.5 MB

// deep pipeline: 6 rotating 20KB dynamic-LDS stages, 5 chunks in flight
constexpr int    NSTAGE   = 6;
constexpr size_t STAGE_SZ = 20480;
constexpr size_t DYN_LDS  = NSTAGE * STAGE_SZ + 768;     // 123,648 B (< 128KiB proven)

#define CLB __asm__ volatile("" ::: "memory")

__device__ __forceinline__ float bf2f(u16 u) {
  union { u32 i; float f; } v; v.i = ((u32)u) << 16; return v.f;
}
__device__ __forceinline__ u16 f2bf(float f) {
  union { float f; u32 i; } v; v.f = f;
  u32 r = v.i + 0x7fffu + ((v.i >> 16) & 1u);
  return (u16)(r >> 16);
}

// async global->LDS, 16B per lane (wave-uniform LDS base + lane*16; dests lane-linear)
typedef __attribute__((address_space(1))) const u32 as1_u32;
typedef __attribute__((address_space(3))) u32 as3_u32;
__device__ __forceinline__ void gload_lds16(const u16* g, u16* l) {
  __builtin_amdgcn_global_load_lds((as1_u32*)g, (as3_u32*)l, 16, 0, 0);
}
// SC1 (aux=16): agent-scope read, bypasses XCD-local L1/L2 — used ONLY for h-ring
// reads (cross-XCD producer->consumer). Verified correct in round 2 (passed, and
// removing the L2-invalidating __threadfence left FETCH unchanged -> weights were
// already resident; ring reads are the compulsory cross-XCD traffic).
__device__ __forceinline__ void gload_lds16_dc(const u16* g, u16* l) {
  __builtin_amdgcn_global_load_lds((as1_u32*)g, (as3_u32*)l, 16, 0, 16);
}

// ---------------------------------------------------------------- zero
__global__ void k_zero(uint4* p, int n) {
  uint4 z = make_uint4(0u, 0u, 0u, 0u);
  for (int i = blockIdx.x * 256 + threadIdx.x; i < n; i += gridDim.x * 256) p[i] = z;
}

// ---------------------------------------------------------------- weight pack
__global__ void k_pack_w(const float* __restrict__ wih0, const float* __restrict__ whh0,
                         const float* __restrict__ wih1, const float* __restrict__ whh1,
                         const float* __restrict__ wih2, const float* __restrict__ whh2,
                         u16* __restrict__ W0, u16* __restrict__ W1, u16* __restrict__ W2) {
  int idx = blockIdx.x * 256 + threadIdx.x;
  if (idx < L0N) {
    int col = idx / 832, k = idx - col * 832;
    int ntile = col / 192, p = col - ntile * 192;
    int g = p / 48, hc = p - g * 48;
    int gcol = g * 768 + ntile * 48 + hc;
    float v = (k < 40) ? wih0[gcol * 40 + k]
                       : ((k < 64) ? 0.f : whh0[(size_t)gcol * 768 + (k - 64)]);
    W0[idx] = f2bf(v);
  } else if (idx < L0N + L12N) {
    int li = idx - L0N;
    int col = li / 1536, k = li - col * 1536;
    int ntile = col / 192, p = col - ntile * 192;
    int g = p / 48, hc = p - g * 48;
    int gcol = g * 768 + ntile * 48 + hc;
    float v = (k < 768) ? wih1[(size_t)gcol * 768 + k] : whh1[(size_t)gcol * 768 + (k - 768)];
    W1[li] = f2bf(v);
  } else {
    int li = idx - (L0N + L12N);
    if (li < L12N) {
      int col = li / 1536, k = li - col * 1536;
      int ntile = col / 192, p = col - ntile * 192;
      int g = p / 48, hc = p - g * 48;
      int gcol = g * 768 + ntile * 48 + hc;
      float v = (k < 768) ? wih2[(size_t)gcol * 768 + k] : whh2[(size_t)gcol * 768 + (k - 768)];
      W2[li] = f2bf(v);
    }
  }
}

// ---------------------------------------------------------------- bias pack
__global__ void k_pack_b(const float* __restrict__ bi0, const float* __restrict__ bh0,
                         const float* __restrict__ bi1, const float* __restrict__ bh1,
                         const float* __restrict__ bi2, const float* __restrict__ bh2,
                         float* __restrict__ pbo) {
  int idx = blockIdx.x * 256 + threadIdx.x;   // 3*3072
  int l = idx / 3072, r = idx - l * 3072;
  int ntile = r / 192, p = r - ntile * 192;
  int g = p / 48, hc = p - g * 48;
  int gcol = g * 768 + ntile * 48 + hc;
  const float* bi = (l == 0) ? bi0 : ((l == 1) ? bi1 : bi2);
  const float* bh = (l == 0) ? bh0 : ((l == 1) ? bh1 : bh2);
  pbo[idx] = bi[gcol] + bh[gcol];
}

// ---------------------------------------------------------------- x transform
__global__ void k_xT(const float* __restrict__ x, u16* __restrict__ xT) {
  int idx = blockIdx.x * 256 + threadIdx.x;    // 180*512*64
  int t = idx / (512 * 64);
  int r = idx - t * 512 * 64;
  int b = r >> 6, j = r & 63;
  float v = (j < 40) ? x[((size_t)b * 180 + t) * 40 + j] : 0.f;
  xT[(size_t)t * 32768 + (size_t)(j >> 5) * 16384 + b * 32 + (j & 31)] = f2bf(v);
}

// ================================================================ LSTM kernel body
// Shared by both variants via macro: DEEP=1 -> 6 dynamic-LDS stages, 5 chunks in
// flight (vmcnt(20) steady, tail 15/10/5/0); DEEP=0 -> round-2 proven static 3-stage
// depth-2 (vmcnt(5) steady). Everything else identical.
#define LSTM_BODY(SMEM_DECL, SMEM_PTR, NSTG, DEEP)                                     \
  SMEM_DECL;                                                                           \
  u16*   scr = (u16*)(SMEM_PTR);                                                       \
  float* pbs = (float*)((SMEM_PTR) + (size_t)(NSTG) * STAGE_SZ);                       \
  const int tid = threadIdx.x;                                                         \
  const int bid = blockIdx.x;                                                          \
  const int xcd = bid & 7, j0 = bid >> 3;                                              \
  const int g_    = (j0 >> 2) * 8 + xcd;                                               \
  const int mt    = j0 & 3;                                                            \
  const int layer = g_ >> 4;                                                           \
  const int ntile = g_ & 15;                                                           \
  const int mrow0 = mt * 128;                                                          \
  const u16* Wl     = (layer == 0) ? W0 : ((layer == 1) ? W1 : W2);                    \
  const int  Kl     = (layer == 0) ? 832 : 1536;                                       \
  const int  KcIn   = (layer == 0) ? 2 : 24;                                           \
  const int  nch    = (layer == 0) ? 26 : 48;                                          \
  const u16* inseq  = (layer == 1) ? ring0 : ring1;                                    \
  u16*       ringS  = (layer == 0) ? ring0 : ((layer == 1) ? ring1 : ring2);           \
  const u16* bbase0 = Wl + (size_t)(ntile * 192) * Kl;                                 \
  for (int i = tid; i < 192; i += 256) pbs[i] = pb[layer * 3072 + ntile * 192 + i];    \
  const int wid = tid >> 6, lane = tid & 63;                                           \
  const int wm = wid & 1, wn = wid >> 1;                                               \
  const int l31 = lane & 31, lhi = lane >> 5;                                          \
  float c_reg[24];                                                                     \
  _Pragma("unroll")                                                                    \
  for (int i = 0; i < 24; i++) c_reg[i] = 0.f;                                         \
  for (int s = 0; s < kT + 2; ++s) {                                                   \
    const int t = s - layer;                                                           \
    if (t >= 0 && t < kT) {                                                            \
      f32x16 acc[2][3];                                                                \
      _Pragma("unroll")                                                                \
      for (int mi = 0; mi < 2; mi++)                                                   \
        for (int ni = 0; ni < 3; ni++)                                                 \
          for (int r = 0; r < 16; r++) acc[mi][ni][r] = 0.f;                           \
      const u16* inbase  = (layer == 0) ? (xT + (size_t)t * 32768)                     \
                                        : (inseq + (size_t)(t & 1) * RING_SLOT_E);     \
      const u16* recbase = ringS + (size_t)((t - 1) & 1) * RING_SLOT_E;                \
      auto stage = [&](int c, int st) {                                                \
        u16* sbA = (u16*)((SMEM_PTR) + (size_t)st * STAGE_SZ);                         \
        u16* sbB = sbA + 4096;                                                         \
        const bool rsrc = (layer != 0) || (c >= KcIn);                                 \
        const u16* abase = (c < KcIn) ? (inbase + (size_t)c * 16384)                   \
                                      : (recbase + (size_t)(c - KcIn) * 16384);        \
        _Pragma("unroll")                                                              \
        for (int k = 0; k < 2; k++) {                                                  \
          const int e = tid + k * 256;                                                 \
          const int row = e >> 2, sp = e & 3;                                          \
          const int so = sp ^ ((row >> 1) & 3);                                        \
          const u16* ga = abase + (size_t)(mrow0 + row) * 32 + so * 8;                 \
          u16*       la = sbA + (size_t)e * 8;                                         \
          if (rsrc) gload_lds16_dc(ga, la);                                            \
          else      gload_lds16(ga, la);                                               \
        }                                                                              \
        const u16* bb = bbase0 + c * 32;                                               \
        _Pragma("unroll")                                                              \
        for (int k = 0; k < 3; k++) {                                                  \
          const int e = tid + k * 256;                                                 \
          const int col = e >> 2, sp = e & 3;                                          \
          const int so = sp ^ ((col >> 1) & 3);                                        \
          gload_lds16(bb + (size_t)col * Kl + so * 8, sbB + (size_t)e * 8);            \
        }                                                                              \
      };                                                                               \
      if (DEEP) { stage(0,0); stage(1,1); stage(2,2); stage(3,3); stage(4,4); }        \
      else      { stage(0,0); stage(1,1); }                                            \
      for (int c = 0; c < nch; ++c) {                                                  \
        CLB;                                                                           \
        const int rem = nch - 1 - c;                                                   \
        if (DEEP) {                                                                    \
          switch (rem > 4 ? 4 : rem) {                                                 \
            case 0:  __builtin_amdgcn_s_waitcnt(0x0F70); break; /* vmcnt(0)  */        \
            case 1:  __builtin_amdgcn_s_waitcnt(0x0F75); break; /* vmcnt(5)  */        \
            case 2:  __builtin_amdgcn_s_waitcnt(0x0F7A); break; /* vmcnt(10) */        \
            case 3:  __builtin_amdgcn_s_waitcnt(0x0F7F); break; /* vmcnt(15) */        \
            default: __builtin_amdgcn_s_waitcnt(0x4F74); break; /* vmcnt(20) */        \
          }                                                                            \
        } else {                                                                       \
          if (rem == 0) __builtin_amdgcn_s_waitcnt(0x0F70);     /* vmcnt(0)  */        \
          else          __builtin_amdgcn_s_waitcnt(0x0F75);     /* vmcnt(5)  */        \
        }                                                                              \
        __builtin_amdgcn_s_barrier();                                                  \
        CLB;                                                                           \
        const int pf = DEEP ? 5 : 2;                                                   \
        if (c + pf < nch) stage(c + pf, (c + pf) % (NSTG));                            \
        const u16* sA = (const u16*)((SMEM_PTR) + (size_t)(c % (NSTG)) * STAGE_SZ);    \
        const u16* sB = sA + 4096;                                                     \
        const int wsw = (l31 >> 1) & 3;                                                \
        _Pragma("unroll")                                                              \
        for (int kk = 0; kk < 2; kk++) {                                               \
          const int sl = (((kk << 1) | lhi) ^ wsw) << 3;                               \
          bf16x8 a0 = *(const bf16x8*)(sA + (wm * 64 +      l31) * 32 + sl);           \
          bf16x8 a1 = *(const bf16x8*)(sA + (wm * 64 + 32 + l31) * 32 + sl);           \
          const int c0 = wn * 96 + l31;                                                \
          bf16x8 b0 = *(const bf16x8*)(sB + (c0     ) * 32 + sl);                      \
          bf16x8 b1 = *(const bf16x8*)(sB + (c0 + 32) * 32 + sl);                      \
          bf16x8 b2 = *(const bf16x8*)(sB + (c0 + 64) * 32 + sl);                      \
          acc[0][0] = __builtin_amdgcn_mfma_f32_32x32x16_bf16(a0, b0, acc[0][0],0,0,0);\
          acc[0][1] = __builtin_amdgcn_mfma_f32_32x32x16_bf16(a0, b1, acc[0][1],0,0,0);\
          acc[0][2] = __builtin_amdgcn_mfma_f32_32x32x16_bf16(a0, b2, acc[0][2],0,0,0);\
          acc[1][0] = __builtin_amdgcn_mfma_f32_32x32x16_bf16(a1, b0, acc[1][0],0,0,0);\
          acc[1][1] = __builtin_amdgcn_mfma_f32_32x32x16_bf16(a1, b1, acc[1][1],0,0,0);\
          acc[1][2] = __builtin_amdgcn_mfma_f32_32x32x16_bf16(a1, b2, acc[1][2],0,0,0);\
        }                                                                              \
      }                                                                                \
      __syncthreads();                                                                 \
      _Pragma("unroll")                                                                \
      for (int mi = 0; mi < 2; mi++) {                                                 \
        _Pragma("unroll")                                                              \
        for (int ni = 0; ni < 3; ni++) {                                               \
          const int pcol = wn * 96 + ni * 32 + l31;                                    \
          const int gg = pcol / 48;                                                    \
          const float bias = pbs[pcol];                                                \
          _Pragma("unroll")                                                            \
          for (int r = 0; r < 16; r++) {                                               \
            const int rowl = wm * 64 + mi * 32 + (r & 3) + ((r >> 2) << 3) + (lhi << 2);\
            float v = acc[mi][ni][r] + bias;                                           \
            v = (gg == 2) ? tanhf(v) : (1.f / (1.f + __expf(-v)));                     \
            scr[rowl * 192 + pcol] = f2bf(v);                                          \
          }                                                                            \
        }                                                                              \
      }                                                                                \
      __syncthreads();                                                                 \
      u16* hout = ringS + (size_t)(t & 1) * RING_SLOT_E;                               \
      _Pragma("unroll")                                                                \
      for (int jj = 0; jj < 24; jj++) {                                                \
        const int idx = jj * 256 + tid;                                                \
        const int row = idx / 48;                                                      \
        const int hc  = idx - row * 48;                                                \
        const float iv = bf2f(scr[row * 192       + hc]);                              \
        const float fv = bf2f(scr[row * 192 +  48 + hc]);                              \
        const float gv = bf2f(scr[row * 192 +  96 + hc]);                              \
        const float ov = bf2f(scr[row * 192 + 144 + hc]);                              \
        const float cn = fv * c_reg[jj] + iv * gv;                                     \
        c_reg[jj] = cn;                                                                \
        const int colg = ntile * 48 + hc;                                              \
        hout[(size_t)(colg >> 5) * 16384 + (size_t)(mrow0 + row) * 32 + (colg & 31)]   \
            = f2bf(ov * tanhf(cn));                                                    \
      }                                                                                \
    }                                                                                  \
    __syncthreads();                                                                   \
    if (tid == 0) {                                                                    \
      __hip_atomic_fetch_add(bar, 1u, __ATOMIC_RELEASE, __HIP_MEMORY_SCOPE_AGENT);     \
      const u32 goal = (u32)(s + 1) * (u32)NBLK;                                       \
      u32 tries = 0;                                                                   \
      while (__hip_atomic_load(bar, __ATOMIC_RELAXED, __HIP_MEMORY_SCOPE_AGENT) < goal) {\
        __builtin_amdgcn_s_sleep(8);                                                   \
        if (++tries > 100000u) break;                                                  \
      }                                                                                \
    }                                                                                  \
    __syncthreads();                                                                   \
  }

// deep variant: 6 dynamic-LDS stages, 5 chunks in flight
__global__ __launch_bounds__(256, 1) void k_lstm_deep(
    const u16* __restrict__ xT,
    u16* __restrict__ ring0, u16* __restrict__ ring1, u16* __restrict__ ring2,
    const u16* __restrict__ W0, const u16* __restrict__ W1, const u16* __restrict__ W2,
    const float* __restrict__ pb, u32* __restrict__ bar) {
  LSTM_BODY(extern __shared__ __align__(16) unsigned char smem[], smem, NSTAGE, 1)
}

// static fallback: byte-identical to round-2's proven kernel (3 stages, depth 2)
__global__ __launch_bounds__(256, 2) void k_lstm(
    const u16* __restrict__ xT,
    u16* __restrict__ ring0, u16* __restrict__ ring1, u16* __restrict__ ring2,
    const u16* __restrict__ W0, const u16* __restrict__ W1, const u16* __restrict__ W2,
    const float* __restrict__ pb, u32* __restrict__ bar) {
  LSTM_BODY(__shared__ __align__(16) unsigned char smem[61440 + 768], smem, 3, 0)
}

// ---------------------------------------------------------------- projection + L2 norm
__global__ __launch_bounds__(256) void k_proj(const u16* __restrict__ hlast,
                                              const float* __restrict__ pw,
                                              const float* __restrict__ pbv,
                                              float* __restrict__ out) {
  __shared__ float hs[8 * 768];
  __shared__ float wred[4 * 8];
  __shared__ float inv[8];
  const int tid = threadIdx.x;
  const int r0 = blockIdx.x * 8;
  for (int i = tid; i < 8 * 768; i += 256) {
    const int b = i / 768, col = i - b * 768;   // chunked ring read
    hs[i] = bf2f(hlast[(size_t)(col >> 5) * 16384 + (size_t)(r0 + b) * 32 + (col & 31)]);
  }
  __syncthreads();
  float acc[8];
#pragma unroll
  for (int r = 0; r < 8; r++) acc[r] = 0.f;
  const float* wrow = pw + (size_t)tid * 768;
  for (int k = 0; k < 768; k++) {
    float w = wrow[k];
#pragma unroll
    for (int r = 0; r < 8; r++) acc[r] += hs[r * 768 + k] * w;
  }
  const float bv = pbv[tid];
#pragma unroll
  for (int r = 0; r < 8; r++) acc[r] += bv;
  const int lane = tid & 63, w4 = tid >> 6;
#pragma unroll
  for (int r = 0; r < 8; r++) {
    float v = acc[r] * acc[r];
#pragma unroll
    for (int off = 32; off > 0; off >>= 1) v += __shfl_xor(v, off);
    if (lane == 0) wred[w4 * 8 + r] = v;
  }
  __syncthreads();
  if (tid < 8) {
    float sum = wred[tid] + wred[8 + tid] + wred[16 + tid] + wred[24 + tid];
    inv[tid] = 1.f / sqrtf(sum);
  }
  __syncthreads();
#pragma unroll
  for (int r = 0; r < 8; r++) out[(size_t)(r0 + r) * 256 + tid] = acc[r] * inv[r];
}

// ---------------------------------------------------------------- host
extern "C" void kernel_launch(void* const* d_in, const int* in_sizes, int n_in,
                              void* d_out, int out_size, void* d_ws, size_t ws_size,
                              hipStream_t stream) {
  const float* x    = (const float*)d_in[0];
  const float* wih0 = (const float*)d_in[1];
  const float* whh0 = (const float*)d_in[2];
  const float* bi0  = (const float*)d_in[3];
  const float* bh0  = (const float*)d_in[4];
  const float* wih1 = (const float*)d_in[5];
  const float* whh1 = (const float*)d_in[6];
  const float* bi1  = (const float*)d_in[7];
  const float* bh1  = (const float*)d_in[8];
  const float* wih2 = (const float*)d_in[9];
  const float* whh2 = (const float*)d_in[10];
  const float* bi2  = (const float*)d_in[11];
  const float* bh2  = (const float*)d_in[12];
  const float* pw   = (const float*)d_in[13];
  const float* pbv  = (const float*)d_in[14];

  if (ws_size < WS_NEED) return;   // clean wrong answer, no OOB

  // host-side feasibility check for the deep (dynamic-LDS) variant — pure queries,
  // no stream ops, so graph capture cannot be poisoned. Fallback = proven static.
  static int use_deep = -1;
  if (use_deep < 0) {
    hipError_t e1 = hipFuncSetAttribute((const void*)k_lstm_deep,
                                        hipFuncAttributeMaxDynamicSharedMemorySize,
                                        (int)DYN_LDS);
    int nb = 0;
    hipError_t e2 = hipOccupancyMaxActiveBlocksPerMultiprocessor(
        &nb, k_lstm_deep, 256, (size_t)DYN_LDS);
    use_deep = (e1 == hipSuccess && e2 == hipSuccess && nb >= 1) ? 1 : 0;
  }

  char* ws  = (char*)d_ws;
  u32*  bar = (u32*)(ws + 0);
  u16*  r0  = (u16*)(ws + OFF_R0);
  u16*  r1  = (u16*)(ws + OFF_R1);
  u16*  r2  = (u16*)(ws + OFF_R2);
  float* pb = (float*)(ws + OFF_PB);
  u16*  xT  = (u16*)(ws + OFF_XT);
  u16*  W0  = (u16*)(ws + OFF_W0);
  u16*  W1  = (u16*)(ws + OFF_W1);
  u16*  W2  = (u16*)(ws + OFF_W2);

  hipLaunchKernelGGL(k_zero, dim3(512), dim3(256), 0, stream,
                     (uint4*)ws, (int)(OFF_PB / 16));
  hipLaunchKernelGGL(k_pack_w, dim3((L0N + 2 * L12N + 255) / 256), dim3(256), 0, stream,
                     wih0, whh0, wih1, whh1, wih2, whh2, W0, W1, W2);
  hipLaunchKernelGGL(k_pack_b, dim3(36), dim3(256), 0, stream,
                     bi0, bh0, bi1, bh1, bi2, bh2, pb);
  hipLaunchKernelGGL(k_xT, dim3(kT * kB * 64 / 256), dim3(256), 0, stream, x, xT);

  {
    const u16* xTc = xT; const float* pbc = pb;
    const u16 *W0c = W0, *W1c = W1, *W2c = W2;
    u16 *r0m = r0, *r1m = r1, *r2m = r2; u32* barm = bar;
    void* kargs[] = {(void*)&xTc, (void*)&r0m, (void*)&r1m, (void*)&r2m,
                     (void*)&W0c, (void*)&W1c, (void*)&W2c, (void*)&pbc, (void*)&barm};
    if (use_deep) {
      hipLaunchCooperativeKernel((void*)k_lstm_deep, dim3(NBLK), dim3(256), kargs,
                                 (unsigned int)DYN_LDS, stream);
    } else {
      hipLaunchCooperativeKernel((void*)k_lstm, dim3(NBLK), dim3(256), kargs, 0, stream);
    }
  }

  hipLaunchKernelGGL(k_proj, dim3(64), dim3(256), 0, stream,
                     r2 + (size_t)((kT - 1) & 1) * RING_SLOT_E, pw, pbv, (float*)d_out);
}

// Round 4
// 8498.096 us; speedup vs baseline: 1.1074x; 1.1074x over previous
//
#include <hip/hip_runtime.h>
#include <cstdint>
#include <cstddef>

using u16 = unsigned short;
using u32 = unsigned int;

typedef __attribute__((ext_vector_type(8)))  __bf16 bf16x8;
typedef __attribute__((ext_vector_type(16))) float  f32x16;

constexpr int kB   = 512;
constexpr int kT   = 180;
constexpr int kH   = 768;
constexpr int NBLK = 192;   // 3 layers * (4 m-tiles * 16 n-tiles)

constexpr int L0N  = 16 * 192 * 832;    // layer0 packed weight elems (26 chunks of 32)
constexpr int L12N = 16 * 192 * 1536;   // layer1/2 (48 chunks)

// h-ring: chunked layout [2 slots][24 kchunks][512 rows][32 k] bf16
constexpr int RING_SLOT_E = 24 * 512 * 32;               // 393,216 elems per slot
constexpr size_t RING_SZ  = (size_t)2 * RING_SLOT_E * 2; // 1,572,864 B

// workspace layout (bytes). Flags: 12 x 256B lines at ws+0 (zeroed).
constexpr size_t OFF_R0  = 4096;
constexpr size_t OFF_R1  = OFF_R0 + RING_SZ;
constexpr size_t OFF_R2  = OFF_R1 + RING_SZ;
constexpr size_t OFF_PB  = OFF_R2 + RING_SZ;             // zeroed region end
constexpr size_t OFF_XT  = OFF_PB + (size_t)3 * 3072 * 4;
constexpr size_t OFF_W0  = OFF_XT + (size_t)kT * kB * 64 * 2;
constexpr size_t OFF_W1  = OFF_W0 + (size_t)L0N * 2;
constexpr size_t OFF_W2  = OFF_W1 + (size_t)L12N * 2;
constexpr size_t WS_NEED = OFF_W2 + (size_t)L12N * 2;    // ~40.5 MB

// deep pipeline: 6 rotating 20KB dynamic-LDS stages, 5 chunks in flight
constexpr int    NSTAGE   = 6;
constexpr size_t STAGE_SZ = 20480;
constexpr size_t DYN_LDS  = NSTAGE * STAGE_SZ + 768;     // 123,648 B

#define CLB __asm__ volatile("" ::: "memory")

__device__ __forceinline__ float bf2f(u16 u) {
  union { u32 i; float f; } v; v.i = ((u32)u) << 16; return v.f;
}
__device__ __forceinline__ u16 f2bf(float f) {
  union { float f; u32 i; } v; v.f = f;
  u32 r = v.i + 0x7fffu + ((v.i >> 16) & 1u);
  return (u16)(r >> 16);
}

// async global->LDS, 16B per lane (wave-uniform LDS base + lane*16; dests lane-linear)
typedef __attribute__((address_space(1))) const u32 as1_u32;
typedef __attribute__((address_space(3))) u32 as3_u32;
__device__ __forceinline__ void gload_lds16(const u16* g, u16* l) {
  __builtin_amdgcn_global_load_lds((as1_u32*)g, (as3_u32*)l, 16, 0, 0);
}
// SC1 (aux=16): agent-scope read, bypasses XCD-local L1/L2 — used ONLY for h-ring
// reads (cross-XCD producer->consumer). Proven correct rounds 2-3. Required here:
// dataflow flags + SC1 reads = no stale-line hazard without any cache invalidation.
__device__ __forceinline__ void gload_lds16_dc(const u16* g, u16* l) {
  __builtin_amdgcn_global_load_lds((as1_u32*)g, (as3_u32*)l, 16, 0, 16);
}

// ---------------------------------------------------------------- zero
__global__ void k_zero(uint4* p, int n) {
  uint4 z = make_uint4(0u, 0u, 0u, 0u);
  for (int i = blockIdx.x * 256 + threadIdx.x; i < n; i += gridDim.x * 256) p[i] = z;
}

// ---------------------------------------------------------------- weight pack
__global__ void k_pack_w(const float* __restrict__ wih0, const float* __restrict__ whh0,
                         const float* __restrict__ wih1, const float* __restrict__ whh1,
                         const float* __restrict__ wih2, const float* __restrict__ whh2,
                         u16* __restrict__ W0, u16* __restrict__ W1, u16* __restrict__ W2) {
  int idx = blockIdx.x * 256 + threadIdx.x;
  if (idx < L0N) {
    int col = idx / 832, k = idx - col * 832;
    int ntile = col / 192, p = col - ntile * 192;
    int g = p / 48, hc = p - g * 48;
    int gcol = g * 768 + ntile * 48 + hc;
    float v = (k < 40) ? wih0[gcol * 40 + k]
                       : ((k < 64) ? 0.f : whh0[(size_t)gcol * 768 + (k - 64)]);
    W0[idx] = f2bf(v);
  } else if (idx < L0N + L12N) {
    int li = idx - L0N;
    int col = li / 1536, k = li - col * 1536;
    int ntile = col / 192, p = col - ntile * 192;
    int g = p / 48, hc = p - g * 48;
    int gcol = g * 768 + ntile * 48 + hc;
    float v = (k < 768) ? wih1[(size_t)gcol * 768 + k] : whh1[(size_t)gcol * 768 + (k - 768)];
    W1[li] = f2bf(v);
  } else {
    int li = idx - (L0N + L12N);
    if (li < L12N) {
      int col = li / 1536, k = li - col * 1536;
      int ntile = col / 192, p = col - ntile * 192;
      int g = p / 48, hc = p - g * 48;
      int gcol = g * 768 + ntile * 48 + hc;
      float v = (k < 768) ? wih2[(size_t)gcol * 768 + k] : whh2[(size_t)gcol * 768 + (k - 768)];
      W2[li] = f2bf(v);
    }
  }
}

// ---------------------------------------------------------------- bias pack
__global__ void k_pack_b(const float* __restrict__ bi0, const float* __restrict__ bh0,
                         const float* __restrict__ bi1, const float* __restrict__ bh1,
                         const float* __restrict__ bi2, const float* __restrict__ bh2,
                         float* __restrict__ pbo) {
  int idx = blockIdx.x * 256 + threadIdx.x;   // 3*3072
  int l = idx / 3072, r = idx - l * 3072;
  int ntile = r / 192, p = r - ntile * 192;
  int g = p / 48, hc = p - g * 48;
  int gcol = g * 768 + ntile * 48 + hc;
  const float* bi = (l == 0) ? bi0 : ((l == 1) ? bi1 : bi2);
  const float* bh = (l == 0) ? bh0 : ((l == 1) ? bh1 : bh2);
  pbo[idx] = bi[gcol] + bh[gcol];
}

// ---------------------------------------------------------------- x transform
__global__ void k_xT(const float* __restrict__ x, u16* __restrict__ xT) {
  int idx = blockIdx.x * 256 + threadIdx.x;    // 180*512*64
  int t = idx / (512 * 64);
  int r = idx - t * 512 * 64;
  int b = r >> 6, j = r & 63;
  float v = (j < 40) ? x[((size_t)b * 180 + t) * 40 + j] : 0.f;
  xT[(size_t)t * 32768 + (size_t)(j >> 5) * 16384 + b * 32 + (j & 31)] = f2bf(v);
}

// ================================================================ LSTM kernel body
// DATAFLOW SYNC (round 4): the 182-global-barrier lockstep is replaced with 12
// counting flags F[layer][mt] (one 256B line each). Block (l,ntile,mt) consumes only
// h-rows [mt*128, mt*128+128), produced exactly by the 16 blocks (l',*,mt):
//   input ready (l>=1):  F[l-1][mt] >= 16*(t+1)
//   recurrence  (t>=1):  F[l][mt]   >= 16*t
//   WAR backpressure (l<=1, t>=2): F[l+1][mt] >= 16*(t-1)   [2-slot ring reuse]
// Producer increments F[l][mt] (RELEASE, agent: wbl2 publishes dirty h) after its
// h-write; consumers read rings SC1 (coherence point) -> no stale lines, no
// invalidation, no 192-way atomic serialization, no global straggler coupling.
// Deadlock-free by induction on (t, layer); spins keep a bounded-tries safety valve.
//
// K-loop: proven homogeneous glds/vmcnt skeleton. DEEP=1: 6 dynamic-LDS stages,
// 5 chunks in flight (vmcnt(20) steady, tail 15/10/5/0). DEEP=0: static 3-stage
// depth-2 (vmcnt(5) steady).
#define LSTM_BODY(SMEM_DECL, SMEM_PTR, NSTG, DEEP)                                     \
  SMEM_DECL;                                                                           \
  u16*   scr = (u16*)(SMEM_PTR);                                                       \
  float* pbs = (float*)((SMEM_PTR) + (size_t)(NSTG) * STAGE_SZ);                       \
  const int tid = threadIdx.x;                                                         \
  const int bid = blockIdx.x;                                                          \
  const int xcd = bid & 7, j0 = bid >> 3;                                              \
  const int g_    = (j0 >> 2) * 8 + xcd;                                               \
  const int mt    = j0 & 3;                                                            \
  const int layer = g_ >> 4;                                                           \
  const int ntile = g_ & 15;                                                           \
  const int mrow0 = mt * 128;                                                          \
  const u16* Wl     = (layer == 0) ? W0 : ((layer == 1) ? W1 : W2);                    \
  const int  Kl     = (layer == 0) ? 832 : 1536;                                       \
  const int  KcIn   = (layer == 0) ? 2 : 24;                                           \
  const int  nch    = (layer == 0) ? 26 : 48;                                          \
  const u16* inseq  = (layer == 1) ? ring0 : ring1;                                    \
  u16*       ringS  = (layer == 0) ? ring0 : ((layer == 1) ? ring1 : ring2);           \
  const u16* bbase0 = Wl + (size_t)(ntile * 192) * Kl;                                 \
  u32* Fself = flg + (size_t)(((layer << 2) | mt) * 64);                               \
  u32* Fin   = flg + (size_t)((((layer - 1) << 2) | mt) * 64);  /* valid if l>=1 */    \
  u32* Fnxt  = flg + (size_t)((((layer + 1) << 2) | mt) * 64);  /* valid if l<=1 */    \
  for (int i = tid; i < 192; i += 256) pbs[i] = pb[layer * 3072 + ntile * 192 + i];    \
  const int wid = tid >> 6, lane = tid & 63;                                           \
  const int wm = wid & 1, wn = wid >> 1;                                               \
  const int l31 = lane & 31, lhi = lane >> 5;                                          \
  float c_reg[24];                                                                     \
  _Pragma("unroll")                                                                    \
  for (int i = 0; i < 24; i++) c_reg[i] = 0.f;                                         \
  for (int t = 0; t < kT; ++t) {                                                       \
    if (tid == 0) {                                                                    \
      auto spinf = [&](u32* f, u32 goal) {                                             \
        u32 tries = 0;                                                                 \
        while (__hip_atomic_load(f, __ATOMIC_RELAXED, __HIP_MEMORY_SCOPE_AGENT) < goal) {\
          __builtin_amdgcn_s_sleep(4);                                                 \
          if (++tries > 400000u) break;                                                \
        }                                                                              \
      };                                                                               \
      if (layer >= 1)           spinf(Fin,   16u * (u32)(t + 1));                      \
      if (t >= 1)               spinf(Fself, 16u * (u32)t);                            \
      if (layer <= 1 && t >= 2) spinf(Fnxt,  16u * (u32)(t - 1));                      \
    }                                                                                  \
    __syncthreads();                                                                   \
    {                                                                                  \
      f32x16 acc[2][3];                                                                \
      _Pragma("unroll")                                                                \
      for (int mi = 0; mi < 2; mi++)                                                   \
        for (int ni = 0; ni < 3; ni++)                                                 \
          for (int r = 0; r < 16; r++) acc[mi][ni][r] = 0.f;                           \
      const u16* inbase  = (layer == 0) ? (xT + (size_t)t * 32768)                     \
                                        : (inseq + (size_t)(t & 1) * RING_SLOT_E);     \
      const u16* recbase = ringS + (size_t)((t - 1) & 1) * RING_SLOT_E;                \
      auto stage = [&](int c, int st) {                                                \
        u16* sbA = (u16*)((SMEM_PTR) + (size_t)st * STAGE_SZ);                         \
        u16* sbB = sbA + 4096;                                                         \
        const bool rsrc = (layer != 0) || (c >= KcIn);                                 \
        const u16* abase = (c < KcIn) ? (inbase + (size_t)c * 16384)                   \
                                      : (recbase + (size_t)(c - KcIn) * 16384);        \
        _Pragma("unroll")                                                              \
        for (int k = 0; k < 2; k++) {                                                  \
          const int e = tid + k * 256;                                                 \
          const int row = e >> 2, sp = e & 3;                                          \
          const int so = sp ^ ((row >> 1) & 3);                                        \
          const u16* ga = abase + (size_t)(mrow0 + row) * 32 + so * 8;                 \
          u16*       la = sbA + (size_t)e * 8;                                         \
          if (rsrc) gload_lds16_dc(ga, la);                                            \
          else      gload_lds16(ga, la);                                               \
        }                                                                              \
        const u16* bb = bbase0 + c * 32;                                               \
        _Pragma("unroll")                                                              \
        for (int k = 0; k < 3; k++) {                                                  \
          const int e = tid + k * 256;                                                 \
          const int col = e >> 2, sp = e & 3;                                          \
          const int so = sp ^ ((col >> 1) & 3);                                        \
          gload_lds16(bb + (size_t)col * Kl + so * 8, sbB + (size_t)e * 8);            \
        }                                                                              \
      };                                                                               \
      if (DEEP) { stage(0,0); stage(1,1); stage(2,2); stage(3,3); stage(4,4); }        \
      else      { stage(0,0); stage(1,1); }                                            \
      for (int c = 0; c < nch; ++c) {                                                  \
        CLB;                                                                           \
        const int rem = nch - 1 - c;                                                   \
        if (DEEP) {                                                                    \
          switch (rem > 4 ? 4 : rem) {                                                 \
            case 0:  __builtin_amdgcn_s_waitcnt(0x0F70); break; /* vmcnt(0)  */        \
            case 1:  __builtin_amdgcn_s_waitcnt(0x0F75); break; /* vmcnt(5)  */        \
            case 2:  __builtin_amdgcn_s_waitcnt(0x0F7A); break; /* vmcnt(10) */        \
            case 3:  __builtin_amdgcn_s_waitcnt(0x0F7F); break; /* vmcnt(15) */        \
            default: __builtin_amdgcn_s_waitcnt(0x4F74); break; /* vmcnt(20) */        \
          }                                                                            \
        } else {                                                                       \
          if (rem == 0) __builtin_amdgcn_s_waitcnt(0x0F70);     /* vmcnt(0)  */        \
          else          __builtin_amdgcn_s_waitcnt(0x0F75);     /* vmcnt(5)  */        \
        }                                                                              \
        __builtin_amdgcn_s_barrier();                                                  \
        CLB;                                                                           \
        const int pf = DEEP ? 5 : 2;                                                   \
        if (c + pf < nch) stage(c + pf, (c + pf) % (NSTG));                            \
        const u16* sA = (const u16*)((SMEM_PTR) + (size_t)(c % (NSTG)) * STAGE_SZ);    \
        const u16* sB = sA + 4096;                                                     \
        const int wsw = (l31 >> 1) & 3;                                                \
        _Pragma("unroll")                                                              \
        for (int kk = 0; kk < 2; kk++) {                                               \
          const int sl = (((kk << 1) | lhi) ^ wsw) << 3;                               \
          bf16x8 a0 = *(const bf16x8*)(sA + (wm * 64 +      l31) * 32 + sl);           \
          bf16x8 a1 = *(const bf16x8*)(sA + (wm * 64 + 32 + l31) * 32 + sl);           \
          const int c0 = wn * 96 + l31;                                                \
          bf16x8 b0 = *(const bf16x8*)(sB + (c0     ) * 32 + sl);                      \
          bf16x8 b1 = *(const bf16x8*)(sB + (c0 + 32) * 32 + sl);                      \
          bf16x8 b2 = *(const bf16x8*)(sB + (c0 + 64) * 32 + sl);                      \
          acc[0][0] = __builtin_amdgcn_mfma_f32_32x32x16_bf16(a0, b0, acc[0][0],0,0,0);\
          acc[0][1] = __builtin_amdgcn_mfma_f32_32x32x16_bf16(a0, b1, acc[0][1],0,0,0);\
          acc[0][2] = __builtin_amdgcn_mfma_f32_32x32x16_bf16(a0, b2, acc[0][2],0,0,0);\
          acc[1][0] = __builtin_amdgcn_mfma_f32_32x32x16_bf16(a1, b0, acc[1][0],0,0,0);\
          acc[1][1] = __builtin_amdgcn_mfma_f32_32x32x16_bf16(a1, b1, acc[1][1],0,0,0);\
          acc[1][2] = __builtin_amdgcn_mfma_f32_32x32x16_bf16(a1, b2, acc[1][2],0,0,0);\
        }                                                                              \
      }                                                                                \
      __syncthreads();                                                                 \
      _Pragma("unroll")                                                                \
      for (int mi = 0; mi < 2; mi++) {                                                 \
        _Pragma("unroll")                                                              \
        for (int ni = 0; ni < 3; ni++) {                                               \
          const int pcol = wn * 96 + ni * 32 + l31;                                    \
          const int gg = pcol / 48;                                                    \
          const float bias = pbs[pcol];                                                \
          _Pragma("unroll")                                                            \
          for (int r = 0; r < 16; r++) {                                               \
            const int rowl = wm * 64 + mi * 32 + (r & 3) + ((r >> 2) << 3) + (lhi << 2);\
            float v = acc[mi][ni][r] + bias;                                           \
            v = (gg == 2) ? tanhf(v) : (1.f / (1.f + __expf(-v)));                     \
            scr[rowl * 192 + pcol] = f2bf(v);                                          \
          }                                                                            \
        }                                                                              \
      }                                                                                \
      __syncthreads();                                                                 \
      u16* hout = ringS + (size_t)(t & 1) * RING_SLOT_E;                               \
      _Pragma("unroll")                                                                \
      for (int jj = 0; jj < 24; jj++) {                                                \
        const int idx = jj * 256 + tid;                                                \
        const int row = idx / 48;                                                      \
        const int hc  = idx - row * 48;                                                \
        const float iv = bf2f(scr[row * 192       + hc]);                              \
        const float fv = bf2f(scr[row * 192 +  48 + hc]);                              \
        const float gv = bf2f(scr[row * 192 +  96 + hc]);                              \
        const float ov = bf2f(scr[row * 192 + 144 + hc]);                              \
        const float cn = fv * c_reg[jj] + iv * gv;                                     \
        c_reg[jj] = cn;                                                                \
        const int colg = ntile * 48 + hc;                                              \
        hout[(size_t)(colg >> 5) * 16384 + (size_t)(mrow0 + row) * 32 + (colg & 31)]   \
            = f2bf(ov * tanhf(cn));                                                    \
      }                                                                                \
    }                                                                                  \
    __syncthreads();  /* drains h-stores (HIP emits vmcnt(0) before s_barrier) */      \
    if (tid == 0)                                                                      \
      __hip_atomic_fetch_add(Fself, 1u, __ATOMIC_RELEASE, __HIP_MEMORY_SCOPE_AGENT);   \
  }

// deep variant: 6 dynamic-LDS stages, 5 chunks in flight
__global__ __launch_bounds__(256, 1) void k_lstm_deep(
    const u16* __restrict__ xT,
    u16* __restrict__ ring0, u16* __restrict__ ring1, u16* __restrict__ ring2,
    const u16* __restrict__ W0, const u16* __restrict__ W1, const u16* __restrict__ W2,
    const float* __restrict__ pb, u32* __restrict__ flg) {
  LSTM_BODY(extern __shared__ __align__(16) unsigned char smem[], smem, NSTAGE, 1)
}

// static fallback: 3 stages, depth 2 (same dataflow sync)
__global__ __launch_bounds__(256, 2) void k_lstm(
    const u16* __restrict__ xT,
    u16* __restrict__ ring0, u16* __restrict__ ring1, u16* __restrict__ ring2,
    const u16* __restrict__ W0, const u16* __restrict__ W1, const u16* __restrict__ W2,
    const float* __restrict__ pb, u32* __restrict__ flg) {
  LSTM_BODY(__shared__ __align__(16) unsigned char smem[61440 + 768], smem, 3, 0)
}

// ---------------------------------------------------------------- projection + L2 norm
__global__ __launch_bounds__(256) void k_proj(const u16* __restrict__ hlast,
                                              const float* __restrict__ pw,
                                              const float* __restrict__ pbv,
                                              float* __restrict__ out) {
  __shared__ float hs[8 * 768];
  __shared__ float wred[4 * 8];
  __shared__ float inv[8];
  const int tid = threadIdx.x;
  const int r0 = blockIdx.x * 8;
  for (int i = tid; i < 8 * 768; i += 256) {
    const int b = i / 768, col = i - b * 768;   // chunked ring read
    hs[i] = bf2f(hlast[(size_t)(col >> 5) * 16384 + (size_t)(r0 + b) * 32 + (col & 31)]);
  }
  __syncthreads();
  float acc[8];
#pragma unroll
  for (int r = 0; r < 8; r++) acc[r] = 0.f;
  const float* wrow = pw + (size_t)tid * 768;
  for (int k = 0; k < 768; k++) {
    float w = wrow[k];
#pragma unroll
    for (int r = 0; r < 8; r++) acc[r] += hs[r * 768 + k] * w;
  }
  const float bv = pbv[tid];
#pragma unroll
  for (int r = 0; r < 8; r++) acc[r] += bv;
  const int lane = tid & 63, w4 = tid >> 6;
#pragma unroll
  for (int r = 0; r < 8; r++) {
    float v = acc[r] * acc[r];
#pragma unroll
    for (int off = 32; off > 0; off >>= 1) v += __shfl_xor(v, off);
    if (lane == 0) wred[w4 * 8 + r] = v;
  }
  __syncthreads();
  if (tid < 8) {
    float sum = wred[tid] + wred[8 + tid] + wred[16 + tid] + wred[24 + tid];
    inv[tid] = 1.f / sqrtf(sum);
  }
  __syncthreads();
#pragma unroll
  for (int r = 0; r < 8; r++) out[(size_t)(r0 + r) * 256 + tid] = acc[r] * inv[r];
}

// ---------------------------------------------------------------- host
extern "C" void kernel_launch(void* const* d_in, const int* in_sizes, int n_in,
                              void* d_out, int out_size, void* d_ws, size_t ws_size,
                              hipStream_t stream) {
  const float* x    = (const float*)d_in[0];
  const float* wih0 = (const float*)d_in[1];
  const float* whh0 = (const float*)d_in[2];
  const float* bi0  = (const float*)d_in[3];
  const float* bh0  = (const float*)d_in[4];
  const float* wih1 = (const float*)d_in[5];
  const float* whh1 = (const float*)d_in[6];
  const float* bi1  = (const float*)d_in[7];
  const float* bh1  = (const float*)d_in[8];
  const float* wih2 = (const float*)d_in[9];
  const float* whh2 = (const float*)d_in[10];
  const float* bi2  = (const float*)d_in[11];
  const float* bh2  = (const float*)d_in[12];
  const float* pw   = (const float*)d_in[13];
  const float* pbv  = (const float*)d_in[14];

  if (ws_size < WS_NEED) return;   // clean wrong answer, no OOB

  // host-side feasibility check for the deep (dynamic-LDS) variant — pure queries,
  // no stream ops, so graph capture cannot be poisoned. Fallback = static 3-stage.
  static int use_deep = -1;
  if (use_deep < 0) {
    hipError_t e1 = hipFuncSetAttribute((const void*)k_lstm_deep,
                                        hipFuncAttributeMaxDynamicSharedMemorySize,
                                        (int)DYN_LDS);
    int nb = 0;
    hipError_t e2 = hipOccupancyMaxActiveBlocksPerMultiprocessor(
        &nb, k_lstm_deep, 256, (size_t)DYN_LDS);
    use_deep = (e1 == hipSuccess && e2 == hipSuccess && nb >= 1) ? 1 : 0;
  }

  char* ws  = (char*)d_ws;
  u32*  flg = (u32*)(ws + 0);
  u16*  r0  = (u16*)(ws + OFF_R0);
  u16*  r1  = (u16*)(ws + OFF_R1);
  u16*  r2  = (u16*)(ws + OFF_R2);
  float* pb = (float*)(ws + OFF_PB);
  u16*  xT  = (u16*)(ws + OFF_XT);
  u16*  W0  = (u16*)(ws + OFF_W0);
  u16*  W1  = (u16*)(ws + OFF_W1);
  u16*  W2  = (u16*)(ws + OFF_W2);

  hipLaunchKernelGGL(k_zero, dim3(512), dim3(256), 0, stream,
                     (uint4*)ws, (int)(OFF_PB / 16));
  hipLaunchKernelGGL(k_pack_w, dim3((L0N + 2 * L12N + 255) / 256), dim3(256), 0, stream,
                     wih0, whh0, wih1, whh1, wih2, whh2, W0, W1, W2);
  hipLaunchKernelGGL(k_pack_b, dim3(36), dim3(256), 0, stream,
                     bi0, bh0, bi1, bh1, bi2, bh2, pb);
  hipLaunchKernelGGL(k_xT, dim3(kT * kB * 64 / 256), dim3(256), 0, stream, x, xT);

  {
    const u16* xTc = xT; const float* pbc = pb;
    const u16 *W0c = W0, *W1c = W1, *W2c = W2;
    u16 *r0m = r0, *r1m = r1, *r2m = r2; u32* flgm = flg;
    void* kargs[] = {(void*)&xTc, (void*)&r0m, (void*)&r1m, (void*)&r2m,
                     (void*)&W0c, (void*)&W1c, (void*)&W2c, (void*)&pbc, (void*)&flgm};
    if (use_deep) {
      hipLaunchCooperativeKernel((void*)k_lstm_deep, dim3(NBLK), dim3(256), kargs,
                                 (unsigned int)DYN_LDS, stream);
    } else {
      hipLaunchCooperativeKernel((void*)k_lstm, dim3(NBLK), dim3(256), kargs, 0, stream);
    }
  }

  hipLaunchKernelGGL(k_proj, dim3(64), dim3(256), 0, stream,
                     r2 + (size_t)((kT - 1) & 1) * RING_SLOT_E, pw, pbv, (float*)d_out);
}